// Round 2
// baseline (1085.546 us; speedup 1.0000x reference)
//
#include <hip/hip_runtime.h>

#define BN_EPS 1e-5f

typedef unsigned int uint_t;
typedef unsigned short ushort_t;

__device__ __forceinline__ float bflo(uint_t v) { return __uint_as_float(v << 16); }
__device__ __forceinline__ float bfhi(uint_t v) { return __uint_as_float(v & 0xffff0000u); }
__device__ __forceinline__ uint_t f2bf(float f) {
    uint_t u = __float_as_uint(f);
    u += 0x7fffu + ((u >> 16) & 1u);
    return u >> 16;
}

// ---------------- CSR build ----------------

__global__ void count_kernel(const int* __restrict__ ei, int* __restrict__ counts, int E) {
    int e = blockIdx.x * blockDim.x + threadIdx.x;
    if (e < E) atomicAdd(&counts[ei[E + e]], 1);
}

__global__ void isd_kernel(const int* __restrict__ counts, float* __restrict__ isd, int N) {
    int n = blockIdx.x * blockDim.x + threadIdx.x;
    if (n < N) isd[n] = rsqrtf((float)counts[n] + 1.0f);
}

// single-block exclusive scan of counts -> rowptr[0..N]
__global__ void scan_kernel(const int* __restrict__ counts, int* __restrict__ rowptr, int n) {
    const int tid = threadIdx.x;
    const int lane = tid & 63, wave = tid >> 6;
    __shared__ int wsum[4];
    __shared__ int s_carry;
    if (tid == 0) s_carry = 0;
    __syncthreads();
    for (int base = 0; base < n; base += 2048) {
        int idx0 = base + tid * 8;
        int v[8];
        int tsum = 0;
#pragma unroll
        for (int j = 0; j < 8; j++) {
            int i = idx0 + j;
            v[j] = (i < n) ? counts[i] : 0;
            tsum += v[j];
        }
        int incl = tsum;
#pragma unroll
        for (int off = 1; off < 64; off <<= 1) {
            int t = __shfl_up(incl, off, 64);
            if (lane >= off) incl += t;
        }
        if (lane == 63) wsum[wave] = incl;
        __syncthreads();
        int wexcl = 0;
        for (int w2 = 0; w2 < wave; w2++) wexcl += wsum[w2];
        int carry = s_carry;
        __syncthreads();
        int run = carry + wexcl + (incl - tsum);
#pragma unroll
        for (int j = 0; j < 8; j++) {
            int i = idx0 + j;
            if (i < n) rowptr[i] = run;
            run += v[j];
        }
        if (tid == 255) s_carry = run;
        __syncthreads();
    }
    if (tid == 0) rowptr[n] = s_carry;
}

__global__ void scatter_kernel(const int* __restrict__ ei, const int* __restrict__ rowptr,
                               int* __restrict__ cursor, const float* __restrict__ isd,
                               int* __restrict__ srcs, float* __restrict__ coefs, int E) {
    int e = blockIdx.x * blockDim.x + threadIdx.x;
    if (e < E) {
        int s = ei[e], d = ei[E + e];
        int p = atomicAdd(&cursor[d], 1);
        int idx = rowptr[d] + p;
        srcs[idx] = s;
        coefs[idx] = isd[s] * isd[d];
    }
}

// ---------------- encoder: h0 = relu(x @ Wenc + benc) + atomic BN stats ----------------

__global__ __launch_bounds__(256) void encoder_kernel(const float* __restrict__ x,
                                                      const float* __restrict__ W,
                                                      const float* __restrict__ b,
                                                      float* __restrict__ h0,
                                                      float* __restrict__ stats, int N) {
    int tid = threadIdx.x;
    int g = blockIdx.x * 256 + tid;
    int total = gridDim.x * 256;
    int c = tid & 127;
    float w0 = W[c], w1 = W[128 + c], w2 = W[256 + c], w3 = W[384 + c], bb = b[c];
    float s = 0.f, q = 0.f;
    int tot = N * 128;
    for (int i = g; i < tot; i += total) {
        int n = i >> 7;
        float4 xv = ((const float4*)x)[n];
        float v = fmaf(xv.x, w0, fmaf(xv.y, w1, fmaf(xv.z, w2, fmaf(xv.w, w3, bb))));
        v = fmaxf(v, 0.f);
        h0[i] = v;
        s += v;
        q += v * v;
    }
    __shared__ float ls[256];
    ls[tid] = s;
    __syncthreads();
    if (tid < 128) atomicAdd(&stats[tid], ls[tid] + ls[tid + 128]);
    __syncthreads();
    ls[tid] = q;
    __syncthreads();
    if (tid < 128) atomicAdd(&stats[128 + tid], ls[tid] + ls[tid + 128]);
}

// ---------------- BN stats finalize (self-zeroing for graph replay) ----------------

__global__ void finalize_stats(float* __restrict__ stats, const float* __restrict__ g,
                               const float* __restrict__ beta, float* __restrict__ ss,
                               float invN) {
    int tid = threadIdx.x;  // 128 threads
    float S = stats[tid], Q = stats[tid + 128];
    float mu = S * invN;
    float var = Q * invN - mu * mu;
    float rs = rsqrtf(var + BN_EPS);
    float scale = g[tid] * rs;
    ss[tid] = scale;
    ss[128 + tid] = beta[tid] - mu * scale;
    stats[tid] = 0.f;
    stats[tid + 128] = 0.f;
}

// ---------------- fused GEMM ----------------
// MODE 0: A = h0*scale + shift (encoder BN apply), write back to hout
// MODE 1: A = h + relu(agg*scale + shift)  (BN+ReLU+residual), optional write back
// MODE 2: A = A0 (plain)
// Output: bf16 (WBF16) to Cb, else f32 (+bias, +relu) to Cf.

template <int K, int NOUT, int MODE, bool RELU, bool WRITE_H, bool WBF16>
__global__ __launch_bounds__(256) void fused_gemm(const float* A0, const float* __restrict__ agg,
                                                  const float* __restrict__ ss,
                                                  const float* __restrict__ B,
                                                  const float* __restrict__ bias, float* hout,
                                                  float* __restrict__ Cf,
                                                  ushort_t* __restrict__ Cb, int N) {
    static_assert(MODE == 2 || K == 128, "ss indexing requires K==128");
    constexpr int TN = NOUT / 16;
    constexpr int LDA = K + 1;
    __shared__ float As[64 * LDA];
    __shared__ float Bs[16 * NOUT];
    const int tid = threadIdx.x;
    const int row0 = blockIdx.x * 64;

    // prologue: build A tile in LDS (and optionally update h in place)
    constexpr int NF4 = 64 * K / 4 / 256;
#pragma unroll
    for (int j = 0; j < NF4; j++) {
        int idx = (j * 256 + tid) * 4;
        int r = idx / K;
        int c = idx % K;
        int grow = row0 + r;
        float4 a = make_float4(0.f, 0.f, 0.f, 0.f);
        if (grow < N) {
            if (MODE == 2) {
                a = *(const float4*)&A0[(size_t)grow * K + c];
            } else {
                float4 sc = *(const float4*)&ss[c];
                float4 sh = *(const float4*)&ss[128 + c];
                float4 hv = *(const float4*)&A0[(size_t)grow * K + c];
                if (MODE == 0) {
                    a.x = fmaf(hv.x, sc.x, sh.x);
                    a.y = fmaf(hv.y, sc.y, sh.y);
                    a.z = fmaf(hv.z, sc.z, sh.z);
                    a.w = fmaf(hv.w, sc.w, sh.w);
                } else {
                    float4 av = *(const float4*)&agg[(size_t)grow * K + c];
                    a.x = hv.x + fmaxf(fmaf(av.x, sc.x, sh.x), 0.f);
                    a.y = hv.y + fmaxf(fmaf(av.y, sc.y, sh.y), 0.f);
                    a.z = hv.z + fmaxf(fmaf(av.z, sc.z, sh.z), 0.f);
                    a.w = hv.w + fmaxf(fmaf(av.w, sc.w, sh.w), 0.f);
                }
                if (WRITE_H) *(float4*)&hout[(size_t)grow * K + c] = a;
            }
        }
        As[r * LDA + c + 0] = a.x;
        As[r * LDA + c + 1] = a.y;
        As[r * LDA + c + 2] = a.z;
        As[r * LDA + c + 3] = a.w;
    }
    __syncthreads();

    float acc[4][TN];
#pragma unroll
    for (int i = 0; i < 4; i++)
#pragma unroll
        for (int j = 0; j < TN; j++) acc[i][j] = 0.f;

    const int tx = tid & 15, ty = tid >> 4;
    for (int k0 = 0; k0 < K; k0 += 16) {
        for (int f = tid; f < 16 * NOUT / 4; f += 256) {
            int r = f / (NOUT / 4), c4 = (f % (NOUT / 4)) * 4;
            *(float4*)&Bs[r * NOUT + c4] = *(const float4*)&B[(size_t)(k0 + r) * NOUT + c4];
        }
        __syncthreads();
#pragma unroll
        for (int kk = 0; kk < 16; ++kk) {
            float a[4], bf[TN];
#pragma unroll
            for (int i = 0; i < 4; i++) a[i] = As[(ty * 4 + i) * LDA + k0 + kk];
#pragma unroll
            for (int j = 0; j < TN; j++) bf[j] = Bs[kk * NOUT + tx * TN + j];
#pragma unroll
            for (int i = 0; i < 4; i++)
#pragma unroll
                for (int j = 0; j < TN; j++) acc[i][j] = fmaf(a[i], bf[j], acc[i][j]);
        }
        __syncthreads();
    }

#pragma unroll
    for (int i = 0; i < 4; i++) {
        int grow = row0 + ty * 4 + i;
        if (grow >= N) continue;
        if (WBF16) {
            uint_t* dst = (uint_t*)&Cb[(size_t)grow * NOUT + tx * TN];
#pragma unroll
            for (int j2 = 0; j2 < TN / 2; j2++) {
                uint_t lo = f2bf(acc[i][2 * j2]);
                uint_t hi = f2bf(acc[i][2 * j2 + 1]);
                dst[j2] = lo | (hi << 16);
            }
        } else {
#pragma unroll
            for (int j = 0; j < TN; j++) {
                int c = tx * TN + j;
                float v = acc[i][j];
                if (bias) v += bias[c];
                if (RELU) v = fmaxf(v, 0.f);
                Cf[(size_t)grow * NOUT + c] = v;
            }
        }
    }
}

// ---------------- aggregation (bf16 gather): agg[n] = sum_in hw[src]*coef + hw[n]*isd^2 ----------------

__global__ __launch_bounds__(256) void agg_kernel(const ushort_t* __restrict__ hwb,
                                                  const int* __restrict__ rowptr,
                                                  const int* __restrict__ srcs,
                                                  const float* __restrict__ coefs,
                                                  const float* __restrict__ isd,
                                                  float* __restrict__ agg,
                                                  float* __restrict__ stats, int N) {
    int tid = threadIdx.x;
    int wave = tid >> 6, lane = tid & 63;
    int c0 = lane << 1;
    float s0 = 0.f, s1 = 0.f, q0 = 0.f, q1 = 0.f;
    for (int n = blockIdx.x * 4 + wave; n < N; n += gridDim.x * 4) {
        int e0 = rowptr[n], e1 = rowptr[n + 1];
        float isdn = isd[n];
        float isdn2 = isdn * isdn;
        uint_t selfv = *(const uint_t*)&hwb[(size_t)n * 128 + c0];
        float a0 = bflo(selfv) * isdn2, a1 = bfhi(selfv) * isdn2;
        for (int e = e0; e < e1; ++e) {
            int sn = srcs[e];
            float w = coefs[e];
            uint_t v = *(const uint_t*)&hwb[(size_t)sn * 128 + c0];
            a0 = fmaf(bflo(v), w, a0);
            a1 = fmaf(bfhi(v), w, a1);
        }
        *(float2*)&agg[(size_t)n * 128 + c0] = make_float2(a0, a1);
        s0 += a0;
        s1 += a1;
        q0 += a0 * a0;
        q1 += a1 * a1;
    }
    __shared__ float ls[4][128];
    ls[wave][c0] = s0;
    ls[wave][c0 + 1] = s1;
    __syncthreads();
    if (tid < 128) atomicAdd(&stats[tid], ls[0][tid] + ls[1][tid] + ls[2][tid] + ls[3][tid]);
    __syncthreads();
    ls[wave][c0] = q0;
    ls[wave][c0 + 1] = q1;
    __syncthreads();
    if (tid < 128) atomicAdd(&stats[128 + tid], ls[0][tid] + ls[1][tid] + ls[2][tid] + ls[3][tid]);
}

// ---------------- decoder final: out = d2 @ W3 + b3 ----------------

__global__ void dec3_kernel(const float* __restrict__ d2, const float* __restrict__ W3,
                            const float* __restrict__ b3, float* __restrict__ out, int N) {
    __shared__ float tile[64 * 33];
    __shared__ float w3s[32];
    int base = blockIdx.x * 64;
    int tid = threadIdx.x;
    if (tid < 32) w3s[tid] = W3[tid];
    for (int f = tid; f < 2048; f += 256) {
        int r = f >> 5, c = f & 31;
        int n = base + r;
        tile[r * 33 + c] = (n < N) ? d2[(size_t)n * 32 + c] : 0.f;
    }
    __syncthreads();
    if (tid < 64) {
        int n = base + tid;
        if (n < N) {
            float s = b3[0];
#pragma unroll
            for (int k = 0; k < 32; k++) s = fmaf(tile[tid * 33 + k], w3s[k], s);
            out[n] = s;
        }
    }
}

// ---------------- host ----------------

extern "C" void kernel_launch(void* const* d_in, const int* in_sizes, int n_in, void* d_out,
                              int out_size, void* d_ws, size_t ws_size, hipStream_t stream) {
    const float* x = (const float*)d_in[0];
    const int* ei = (const int*)d_in[1];
    const float* enc_w = (const float*)d_in[2];
    const float* enc_b = (const float*)d_in[3];
    const float* enc_bn_g = (const float*)d_in[4];
    const float* enc_bn_b = (const float*)d_in[5];
    const float* conv_w = (const float*)d_in[6];
    // d_in[7] = conv_b: cancels in BatchNorm, unused
    const float* bn_g = (const float*)d_in[8];
    const float* bn_b = (const float*)d_in[9];
    const float* dw1 = (const float*)d_in[10];
    const float* db1 = (const float*)d_in[11];
    const float* dw2 = (const float*)d_in[12];
    const float* db2 = (const float*)d_in[13];
    const float* dw3 = (const float*)d_in[14];
    const float* db3 = (const float*)d_in[15];
    float* out = (float*)d_out;

    const int N = in_sizes[0] / 4;  // 50000
    const int E = in_sizes[1] / 2;  // 600000
    const size_t N128 = (size_t)N * 128;

    // workspace layout (~70 MB)
    float* h = (float*)d_ws;              // N x 128 f32
    float* agg = h + N128;                // N x 128 f32
    ushort_t* hwb = (ushort_t*)(agg + N128);  // N x 128 bf16
    float* stats = (float*)(hwb + N128);  // 256
    float* ss = stats + 256;              // 256: scale[128], shift[128]
    float* isd = ss + 256;                // N
    int* counts = (int*)(isd + N);        // N
    int* rowptr = counts + N;             // N+1
    int* cursor = rowptr + N + 1;         // N
    int* srcs = cursor + N;               // E
    float* coefs = (float*)(srcs + E);    // E
    float* d1 = (float*)hwb;              // reuse: N x 64 f32 (same bytes as hwb)
    float* d2 = agg;                      // reuse: N x 32 f32

    hipMemsetAsync(stats, 0, 256 * sizeof(float), stream);
    hipMemsetAsync(counts, 0, (size_t)N * sizeof(int), stream);
    hipMemsetAsync(cursor, 0, (size_t)N * sizeof(int), stream);

    const int eb = (E + 255) / 256;
    count_kernel<<<eb, 256, 0, stream>>>(ei, counts, E);
    isd_kernel<<<(N + 255) / 256, 256, 0, stream>>>(counts, isd, N);
    scan_kernel<<<1, 256, 0, stream>>>(counts, rowptr, N);
    scatter_kernel<<<eb, 256, 0, stream>>>(ei, rowptr, cursor, isd, srcs, coefs, E);

    encoder_kernel<<<1024, 256, 0, stream>>>(x, enc_w, enc_b, h, stats, N);
    finalize_stats<<<1, 128, 0, stream>>>(stats, enc_bn_g, enc_bn_b, ss, 1.0f / N);

    const int gblocks = (N + 63) / 64;
    const float invN = 1.0f / N;

    // layer 0: A = BN(h0) written in place, hwb = A @ W0
    fused_gemm<128, 128, 0, false, true, true>
        <<<gblocks, 256, 0, stream>>>(h, nullptr, ss, conv_w, nullptr, h, nullptr, hwb, N);
    agg_kernel<<<2048, 256, 0, stream>>>(hwb, rowptr, srcs, coefs, isd, agg, stats, N);
    finalize_stats<<<1, 128, 0, stream>>>(stats, bn_g, bn_b, ss, invN);

    for (int l = 1; l < 6; l++) {
        fused_gemm<128, 128, 1, false, true, true><<<gblocks, 256, 0, stream>>>(
            h, agg, ss, conv_w + (size_t)l * 128 * 128, nullptr, h, nullptr, hwb, N);
        agg_kernel<<<2048, 256, 0, stream>>>(hwb, rowptr, srcs, coefs, isd, agg, stats, N);
        finalize_stats<<<1, 128, 0, stream>>>(stats, bn_g + l * 128, bn_b + l * 128, ss, invN);
    }

    // decoder: layer-5 update fused into dec1's prologue (no h write-back needed)
    fused_gemm<128, 64, 1, true, false, false>
        <<<gblocks, 256, 0, stream>>>(h, agg, ss, dw1, db1, nullptr, d1, nullptr, N);
    fused_gemm<64, 32, 2, true, false, false>
        <<<gblocks, 256, 0, stream>>>(d1, nullptr, nullptr, dw2, db2, nullptr, d2, nullptr, N);
    dec3_kernel<<<gblocks, 256, 0, stream>>>(d2, dw3, db3, out, N);
}

// Round 3
// 945.719 us; speedup vs baseline: 1.1479x; 1.1479x over previous
//
#include <hip/hip_runtime.h>

#define BN_EPS 1e-5f

typedef unsigned int uint_t;
typedef unsigned short ushort_t;

__device__ __forceinline__ float bflo(uint_t v) { return __uint_as_float(v << 16); }
__device__ __forceinline__ float bfhi(uint_t v) { return __uint_as_float(v & 0xffff0000u); }
__device__ __forceinline__ uint_t f2bf(float f) {
    uint_t u = __float_as_uint(f);
    u += 0x7fffu + ((u >> 16) & 1u);
    return u >> 16;
}

// ---------------- CSR build ----------------

__global__ void count_kernel(const int* __restrict__ ei, int* __restrict__ counts, int E) {
    int e = blockIdx.x * blockDim.x + threadIdx.x;
    if (e < E) atomicAdd(&counts[ei[E + e]], 1);
}

__global__ void isd_kernel(const int* __restrict__ counts, float* __restrict__ isd, int N) {
    int n = blockIdx.x * blockDim.x + threadIdx.x;
    if (n < N) isd[n] = rsqrtf((float)counts[n] + 1.0f);
}

// single-block exclusive scan of counts -> rowptr[0..N]
__global__ void scan_kernel(const int* __restrict__ counts, int* __restrict__ rowptr, int n) {
    const int tid = threadIdx.x;
    const int lane = tid & 63, wave = tid >> 6;
    __shared__ int wsum[4];
    __shared__ int s_carry;
    if (tid == 0) s_carry = 0;
    __syncthreads();
    for (int base = 0; base < n; base += 2048) {
        int idx0 = base + tid * 8;
        int v[8];
        int tsum = 0;
#pragma unroll
        for (int j = 0; j < 8; j++) {
            int i = idx0 + j;
            v[j] = (i < n) ? counts[i] : 0;
            tsum += v[j];
        }
        int incl = tsum;
#pragma unroll
        for (int off = 1; off < 64; off <<= 1) {
            int t = __shfl_up(incl, off, 64);
            if (lane >= off) incl += t;
        }
        if (lane == 63) wsum[wave] = incl;
        __syncthreads();
        int wexcl = 0;
        for (int w2 = 0; w2 < wave; w2++) wexcl += wsum[w2];
        int carry = s_carry;
        __syncthreads();
        int run = carry + wexcl + (incl - tsum);
#pragma unroll
        for (int j = 0; j < 8; j++) {
            int i = idx0 + j;
            if (i < n) rowptr[i] = run;
            run += v[j];
        }
        if (tid == 255) s_carry = run;
        __syncthreads();
    }
    if (tid == 0) rowptr[n] = s_carry;
}

__global__ void scatter_kernel(const int* __restrict__ ei, const int* __restrict__ rowptr,
                               int* __restrict__ cursor, const float* __restrict__ isd,
                               int* __restrict__ srcs, float* __restrict__ coefs, int E) {
    int e = blockIdx.x * blockDim.x + threadIdx.x;
    if (e < E) {
        int s = ei[e], d = ei[E + e];
        int p = atomicAdd(&cursor[d], 1);
        int idx = rowptr[d] + p;
        srcs[idx] = s;
        coefs[idx] = isd[s] * isd[d];
    }
}

// ---------------- encoder: h0 = relu(x @ Wenc + benc) + atomic BN stats ----------------

__global__ __launch_bounds__(256) void encoder_kernel(const float* __restrict__ x,
                                                      const float* __restrict__ W,
                                                      const float* __restrict__ b,
                                                      float* __restrict__ h0,
                                                      float* __restrict__ stats, int N) {
    int tid = threadIdx.x;
    int g = blockIdx.x * 256 + tid;
    int total = gridDim.x * 256;
    int c = tid & 127;
    float w0 = W[c], w1 = W[128 + c], w2 = W[256 + c], w3 = W[384 + c], bb = b[c];
    float s = 0.f, q = 0.f;
    int tot = N * 128;
    for (int i = g; i < tot; i += total) {
        int n = i >> 7;
        float4 xv = ((const float4*)x)[n];
        float v = fmaf(xv.x, w0, fmaf(xv.y, w1, fmaf(xv.z, w2, fmaf(xv.w, w3, bb))));
        v = fmaxf(v, 0.f);
        h0[i] = v;
        s += v;
        q += v * v;
    }
    __shared__ float ls[256];
    ls[tid] = s;
    __syncthreads();
    if (tid < 128) atomicAdd(&stats[tid], ls[tid] + ls[tid + 128]);
    __syncthreads();
    ls[tid] = q;
    __syncthreads();
    if (tid < 128) atomicAdd(&stats[128 + tid], ls[tid] + ls[tid + 128]);
}

// ---------------- BN stats finalize (self-zeroing for graph replay) ----------------

__global__ void finalize_stats(float* __restrict__ stats, const float* __restrict__ g,
                               const float* __restrict__ beta, float* __restrict__ ss,
                               float invN) {
    int tid = threadIdx.x;  // 128 threads
    float S = stats[tid], Q = stats[tid + 128];
    float mu = S * invN;
    float var = Q * invN - mu * mu;
    float rs = rsqrtf(var + BN_EPS);
    float scale = g[tid] * rs;
    ss[tid] = scale;
    ss[128 + tid] = beta[tid] - mu * scale;
    stats[tid] = 0.f;
    stats[tid + 128] = 0.f;
}

// ---------------- fused GEMM ----------------
// MODE 0: A = h0*scale + shift (encoder BN apply), write back to hout
// MODE 1: A = h + relu(agg*scale + shift)  (BN+ReLU+residual), optional write back
// MODE 2: A = A0 (plain)
// Output: bf16 (WBF16) to Cb, else f32 (+bias, +relu) to Cf.

template <int K, int NOUT, int MODE, bool RELU, bool WRITE_H, bool WBF16>
__global__ __launch_bounds__(256) void fused_gemm(const float* A0, const float* __restrict__ agg,
                                                  const float* __restrict__ ss,
                                                  const float* __restrict__ B,
                                                  const float* __restrict__ bias, float* hout,
                                                  float* __restrict__ Cf,
                                                  ushort_t* __restrict__ Cb, int N) {
    static_assert(MODE == 2 || K == 128, "ss indexing requires K==128");
    constexpr int TN = NOUT / 16;
    constexpr int LDA = K + 1;
    __shared__ float As[64 * LDA];
    __shared__ float Bs[16 * NOUT];
    const int tid = threadIdx.x;
    const int row0 = blockIdx.x * 64;

    // prologue: build A tile in LDS (and optionally update h in place)
    constexpr int NF4 = 64 * K / 4 / 256;
#pragma unroll
    for (int j = 0; j < NF4; j++) {
        int idx = (j * 256 + tid) * 4;
        int r = idx / K;
        int c = idx % K;
        int grow = row0 + r;
        float4 a = make_float4(0.f, 0.f, 0.f, 0.f);
        if (grow < N) {
            if (MODE == 2) {
                a = *(const float4*)&A0[(size_t)grow * K + c];
            } else {
                float4 sc = *(const float4*)&ss[c];
                float4 sh = *(const float4*)&ss[128 + c];
                float4 hv = *(const float4*)&A0[(size_t)grow * K + c];
                if (MODE == 0) {
                    a.x = fmaf(hv.x, sc.x, sh.x);
                    a.y = fmaf(hv.y, sc.y, sh.y);
                    a.z = fmaf(hv.z, sc.z, sh.z);
                    a.w = fmaf(hv.w, sc.w, sh.w);
                } else {
                    float4 av = *(const float4*)&agg[(size_t)grow * K + c];
                    a.x = hv.x + fmaxf(fmaf(av.x, sc.x, sh.x), 0.f);
                    a.y = hv.y + fmaxf(fmaf(av.y, sc.y, sh.y), 0.f);
                    a.z = hv.z + fmaxf(fmaf(av.z, sc.z, sh.z), 0.f);
                    a.w = hv.w + fmaxf(fmaf(av.w, sc.w, sh.w), 0.f);
                }
                if (WRITE_H) *(float4*)&hout[(size_t)grow * K + c] = a;
            }
        }
        As[r * LDA + c + 0] = a.x;
        As[r * LDA + c + 1] = a.y;
        As[r * LDA + c + 2] = a.z;
        As[r * LDA + c + 3] = a.w;
    }
    __syncthreads();

    float acc[4][TN];
#pragma unroll
    for (int i = 0; i < 4; i++)
#pragma unroll
        for (int j = 0; j < TN; j++) acc[i][j] = 0.f;

    const int tx = tid & 15, ty = tid >> 4;
    for (int k0 = 0; k0 < K; k0 += 16) {
        for (int f = tid; f < 16 * NOUT / 4; f += 256) {
            int r = f / (NOUT / 4), c4 = (f % (NOUT / 4)) * 4;
            *(float4*)&Bs[r * NOUT + c4] = *(const float4*)&B[(size_t)(k0 + r) * NOUT + c4];
        }
        __syncthreads();
#pragma unroll
        for (int kk = 0; kk < 16; ++kk) {
            float a[4], bf[TN];
#pragma unroll
            for (int i = 0; i < 4; i++) a[i] = As[(ty * 4 + i) * LDA + k0 + kk];
#pragma unroll
            for (int j = 0; j < TN; j++) bf[j] = Bs[kk * NOUT + tx * TN + j];
#pragma unroll
            for (int i = 0; i < 4; i++)
#pragma unroll
                for (int j = 0; j < TN; j++) acc[i][j] = fmaf(a[i], bf[j], acc[i][j]);
        }
        __syncthreads();
    }

#pragma unroll
    for (int i = 0; i < 4; i++) {
        int grow = row0 + ty * 4 + i;
        if (grow >= N) continue;
        if (WBF16) {
            uint_t* dst = (uint_t*)&Cb[(size_t)grow * NOUT + tx * TN];
#pragma unroll
            for (int j2 = 0; j2 < TN / 2; j2++) {
                uint_t lo = f2bf(acc[i][2 * j2]);
                uint_t hi = f2bf(acc[i][2 * j2 + 1]);
                dst[j2] = lo | (hi << 16);
            }
        } else {
#pragma unroll
            for (int j = 0; j < TN; j++) {
                int c = tx * TN + j;
                float v = acc[i][j];
                if (bias) v += bias[c];
                if (RELU) v = fmaxf(v, 0.f);
                Cf[(size_t)grow * NOUT + c] = v;
            }
        }
    }
}

// ---------------- aggregation (bf16 gather, 4 edge slots x 16 lanes x 8ch) ----------------
// agg[n] = sum_in-edges hw[src]*coef + hw[n]*isd^2, plus BN stats.

__global__ __launch_bounds__(256) void agg_kernel(const ushort_t* __restrict__ hwb,
                                                  const int* __restrict__ rowptr,
                                                  const int* __restrict__ srcs,
                                                  const float* __restrict__ coefs,
                                                  const float* __restrict__ isd,
                                                  float* __restrict__ agg,
                                                  float* __restrict__ stats, int N) {
    const int tid = threadIdx.x;
    const int wave = tid >> 6, lane = tid & 63;
    const int eslot = lane >> 4;       // 4 concurrent edge slots
    const int cbase = (lane & 15) * 8; // 8 channels per lane (16B bf16 load)
    float s[8], q[8];
#pragma unroll
    for (int j = 0; j < 8; j++) {
        s[j] = 0.f;
        q[j] = 0.f;
    }

    for (int n = blockIdx.x * 4 + wave; n < N; n += gridDim.x * 4) {
        const int e0 = rowptr[n], e1 = rowptr[n + 1];
        float a[8];
        if (eslot == 0) {
            float isdn = isd[n];
            float w0 = isdn * isdn;
            uint4 v = *(const uint4*)&hwb[(size_t)n * 128 + cbase];
            a[0] = bflo(v.x) * w0;
            a[1] = bfhi(v.x) * w0;
            a[2] = bflo(v.y) * w0;
            a[3] = bfhi(v.y) * w0;
            a[4] = bflo(v.z) * w0;
            a[5] = bfhi(v.z) * w0;
            a[6] = bflo(v.w) * w0;
            a[7] = bfhi(v.w) * w0;
        } else {
#pragma unroll
            for (int j = 0; j < 8; j++) a[j] = 0.f;
        }
        int e = e0 + eslot;
        int sn = 0;
        float w = 0.f;
        if (e < e1) {
            sn = srcs[e];
            w = coefs[e];
        }
        while (e < e1) {
            int e2 = e + 4;
            int sn2 = 0;
            float w2 = 0.f;
            if (e2 < e1) {  // prefetch next slot's edge to hide the pointer chase
                sn2 = srcs[e2];
                w2 = coefs[e2];
            }
            uint4 v = *(const uint4*)&hwb[(size_t)sn * 128 + cbase];
            a[0] = fmaf(bflo(v.x), w, a[0]);
            a[1] = fmaf(bfhi(v.x), w, a[1]);
            a[2] = fmaf(bflo(v.y), w, a[2]);
            a[3] = fmaf(bfhi(v.y), w, a[3]);
            a[4] = fmaf(bflo(v.z), w, a[4]);
            a[5] = fmaf(bfhi(v.z), w, a[5]);
            a[6] = fmaf(bflo(v.w), w, a[6]);
            a[7] = fmaf(bfhi(v.w), w, a[7]);
            sn = sn2;
            w = w2;
            e = e2;
        }
        // butterfly-fold the 4 edge slots (lanes l, l^16, l^32, l^48)
#pragma unroll
        for (int j = 0; j < 8; j++) {
            a[j] += __shfl_xor(a[j], 16, 64);
            a[j] += __shfl_xor(a[j], 32, 64);
        }
        if (eslot == 0) {
            *(float4*)&agg[(size_t)n * 128 + cbase] = make_float4(a[0], a[1], a[2], a[3]);
            *(float4*)&agg[(size_t)n * 128 + cbase + 4] = make_float4(a[4], a[5], a[6], a[7]);
#pragma unroll
            for (int j = 0; j < 8; j++) {
                s[j] += a[j];
                q[j] += a[j] * a[j];
            }
        }
    }
    // block-level stats reduce: lanes<16 of each wave hold s/q for channels cbase..cbase+7
    __shared__ float ls[4][128];
    if (lane < 16) {
#pragma unroll
        for (int j = 0; j < 8; j++) ls[wave][cbase + j] = s[j];
    }
    __syncthreads();
    if (tid < 128) atomicAdd(&stats[tid], ls[0][tid] + ls[1][tid] + ls[2][tid] + ls[3][tid]);
    __syncthreads();
    if (lane < 16) {
#pragma unroll
        for (int j = 0; j < 8; j++) ls[wave][cbase + j] = q[j];
    }
    __syncthreads();
    if (tid < 128) atomicAdd(&stats[128 + tid], ls[0][tid] + ls[1][tid] + ls[2][tid] + ls[3][tid]);
}

// ---------------- decoder final: out = d2 @ W3 + b3 ----------------

__global__ void dec3_kernel(const float* __restrict__ d2, const float* __restrict__ W3,
                            const float* __restrict__ b3, float* __restrict__ out, int N) {
    __shared__ float tile[64 * 33];
    __shared__ float w3s[32];
    int base = blockIdx.x * 64;
    int tid = threadIdx.x;
    if (tid < 32) w3s[tid] = W3[tid];
    for (int f = tid; f < 2048; f += 256) {
        int r = f >> 5, c = f & 31;
        int n = base + r;
        tile[r * 33 + c] = (n < N) ? d2[(size_t)n * 32 + c] : 0.f;
    }
    __syncthreads();
    if (tid < 64) {
        int n = base + tid;
        if (n < N) {
            float s = b3[0];
#pragma unroll
            for (int k = 0; k < 32; k++) s = fmaf(tile[tid * 33 + k], w3s[k], s);
            out[n] = s;
        }
    }
}

// ---------------- host ----------------

extern "C" void kernel_launch(void* const* d_in, const int* in_sizes, int n_in, void* d_out,
                              int out_size, void* d_ws, size_t ws_size, hipStream_t stream) {
    const float* x = (const float*)d_in[0];
    const int* ei = (const int*)d_in[1];
    const float* enc_w = (const float*)d_in[2];
    const float* enc_b = (const float*)d_in[3];
    const float* enc_bn_g = (const float*)d_in[4];
    const float* enc_bn_b = (const float*)d_in[5];
    const float* conv_w = (const float*)d_in[6];
    // d_in[7] = conv_b: cancels in BatchNorm, unused
    const float* bn_g = (const float*)d_in[8];
    const float* bn_b = (const float*)d_in[9];
    const float* dw1 = (const float*)d_in[10];
    const float* db1 = (const float*)d_in[11];
    const float* dw2 = (const float*)d_in[12];
    const float* db2 = (const float*)d_in[13];
    const float* dw3 = (const float*)d_in[14];
    const float* db3 = (const float*)d_in[15];
    float* out = (float*)d_out;

    const int N = in_sizes[0] / 4;  // 50000
    const int E = in_sizes[1] / 2;  // 600000
    const size_t N128 = (size_t)N * 128;

    // workspace layout (~70 MB)
    float* h = (float*)d_ws;                  // N x 128 f32
    float* agg = h + N128;                    // N x 128 f32
    ushort_t* hwb = (ushort_t*)(agg + N128);  // N x 128 bf16
    float* stats = (float*)(hwb + N128);      // 256
    float* ss = stats + 256;                  // 256: scale[128], shift[128]
    float* isd = ss + 256;                    // N
    int* counts = (int*)(isd + N);            // N
    int* rowptr = counts + N;                 // N+1
    int* cursor = rowptr + N + 1;             // N
    int* srcs = cursor + N;                   // E
    float* coefs = (float*)(srcs + E);        // E
    float* d1 = (float*)hwb;                  // reuse: N x 64 f32 (same bytes as hwb)
    float* d2 = agg;                          // reuse: N x 32 f32

    hipMemsetAsync(stats, 0, 256 * sizeof(float), stream);
    hipMemsetAsync(counts, 0, (size_t)N * sizeof(int), stream);
    hipMemsetAsync(cursor, 0, (size_t)N * sizeof(int), stream);

    const int eb = (E + 255) / 256;
    count_kernel<<<eb, 256, 0, stream>>>(ei, counts, E);
    isd_kernel<<<(N + 255) / 256, 256, 0, stream>>>(counts, isd, N);
    scan_kernel<<<1, 256, 0, stream>>>(counts, rowptr, N);
    scatter_kernel<<<eb, 256, 0, stream>>>(ei, rowptr, cursor, isd, srcs, coefs, E);

    encoder_kernel<<<1024, 256, 0, stream>>>(x, enc_w, enc_b, h, stats, N);
    finalize_stats<<<1, 128, 0, stream>>>(stats, enc_bn_g, enc_bn_b, ss, 1.0f / N);

    const int gblocks = (N + 63) / 64;
    const float invN = 1.0f / N;

    // layer 0: A = BN(h0) written in place, hwb = A @ W0
    fused_gemm<128, 128, 0, false, true, true>
        <<<gblocks, 256, 0, stream>>>(h, nullptr, ss, conv_w, nullptr, h, nullptr, hwb, N);
    agg_kernel<<<2048, 256, 0, stream>>>(hwb, rowptr, srcs, coefs, isd, agg, stats, N);
    finalize_stats<<<1, 128, 0, stream>>>(stats, bn_g, bn_b, ss, invN);

    for (int l = 1; l < 6; l++) {
        fused_gemm<128, 128, 1, false, true, true><<<gblocks, 256, 0, stream>>>(
            h, agg, ss, conv_w + (size_t)l * 128 * 128, nullptr, h, nullptr, hwb, N);
        agg_kernel<<<2048, 256, 0, stream>>>(hwb, rowptr, srcs, coefs, isd, agg, stats, N);
        finalize_stats<<<1, 128, 0, stream>>>(stats, bn_g + l * 128, bn_b + l * 128, ss, invN);
    }

    // decoder: layer-5 update fused into dec1's prologue (no h write-back needed)
    fused_gemm<128, 64, 1, true, false, false>
        <<<gblocks, 256, 0, stream>>>(h, agg, ss, dw1, db1, nullptr, d1, nullptr, N);
    fused_gemm<64, 32, 2, true, false, false>
        <<<gblocks, 256, 0, stream>>>(d1, nullptr, nullptr, dw2, db2, nullptr, d2, nullptr, N);
    dec3_kernel<<<gblocks, 256, 0, stream>>>(d2, dw3, db3, out, N);
}

// Round 5
// 710.628 us; speedup vs baseline: 1.5276x; 1.3308x over previous
//
#include <hip/hip_runtime.h>

#define BN_EPS 1e-5f

typedef unsigned int uint_t;
typedef unsigned short ushort_t;
typedef short bf16x8 __attribute__((ext_vector_type(8)));
typedef float f32x4 __attribute__((ext_vector_type(4)));

__device__ __forceinline__ float bflo(uint_t v) { return __uint_as_float(v << 16); }
__device__ __forceinline__ float bfhi(uint_t v) { return __uint_as_float(v & 0xffff0000u); }
__device__ __forceinline__ uint_t f2bf(float f) {
    uint_t u = __float_as_uint(f);
    u += 0x7fffu + ((u >> 16) & 1u);
    return u >> 16;
}

__device__ __forceinline__ void acc8(float* a, uint4 g, float w) {
    a[0] = fmaf(bflo(g.x), w, a[0]);
    a[1] = fmaf(bfhi(g.x), w, a[1]);
    a[2] = fmaf(bflo(g.y), w, a[2]);
    a[3] = fmaf(bfhi(g.y), w, a[3]);
    a[4] = fmaf(bflo(g.z), w, a[4]);
    a[5] = fmaf(bfhi(g.z), w, a[5]);
    a[6] = fmaf(bflo(g.w), w, a[6]);
    a[7] = fmaf(bfhi(g.w), w, a[7]);
}

// ---------------- CSR build (self-loop as explicit edge, rows padded to %4) ----------------

__global__ void count_kernel(const int* __restrict__ ei, int* __restrict__ counts, int E) {
    int e = blockIdx.x * blockDim.x + threadIdx.x;
    if (e < E) atomicAdd(&counts[ei[E + e]], 1);
}

__global__ void isd_kernel(const int* __restrict__ counts, float* __restrict__ isd, int N) {
    int n = blockIdx.x * blockDim.x + threadIdx.x;
    if (n < N) isd[n] = rsqrtf((float)counts[n] + 1.0f);
}

// single-block exclusive scan of PADDED counts: pad(c) = ceil((c+1)/4)*4  (+1 = self edge)
__global__ void scan_kernel(const int* __restrict__ counts, int* __restrict__ rowptr, int n) {
    const int tid = threadIdx.x;
    const int lane = tid & 63, wave = tid >> 6;
    __shared__ int wsum[4];
    __shared__ int s_carry;
    if (tid == 0) s_carry = 0;
    __syncthreads();
    for (int base = 0; base < n; base += 2048) {
        int idx0 = base + tid * 8;
        int v[8];
        int tsum = 0;
#pragma unroll
        for (int j = 0; j < 8; j++) {
            int i = idx0 + j;
            v[j] = (i < n) ? (((counts[i] + 4) >> 2) << 2) : 0;
            tsum += v[j];
        }
        int incl = tsum;
#pragma unroll
        for (int off = 1; off < 64; off <<= 1) {
            int t = __shfl_up(incl, off, 64);
            if (lane >= off) incl += t;
        }
        if (lane == 63) wsum[wave] = incl;
        __syncthreads();
        int wexcl = 0;
        for (int w2 = 0; w2 < wave; w2++) wexcl += wsum[w2];
        int carry = s_carry;
        __syncthreads();
        int run = carry + wexcl + (incl - tsum);
#pragma unroll
        for (int j = 0; j < 8; j++) {
            int i = idx0 + j;
            if (i < n) rowptr[i] = run;
            run += v[j];
        }
        if (tid == 255) s_carry = run;
        __syncthreads();
    }
    if (tid == 0) rowptr[n] = s_carry;
}

__global__ void scatter_kernel(const int* __restrict__ ei, const int* __restrict__ rowptr,
                               int* __restrict__ cursor, const float* __restrict__ isd,
                               int* __restrict__ srcs, float* __restrict__ coefs, int E) {
    int e = blockIdx.x * blockDim.x + threadIdx.x;
    if (e < E) {
        int s = ei[e], d = ei[E + e];
        int p = atomicAdd(&cursor[d], 1);
        int idx = rowptr[d] + p;
        srcs[idx] = s;
        coefs[idx] = isd[s] * isd[d];
    }
}

__global__ void selfedge_kernel(const int* __restrict__ counts, const int* __restrict__ rowptr,
                                const float* __restrict__ isd, int* __restrict__ srcs,
                                float* __restrict__ coefs, int N) {
    int n = blockIdx.x * blockDim.x + threadIdx.x;
    if (n < N) {
        int pos = rowptr[n] + counts[n];
        float v = isd[n];
        srcs[pos] = n;
        coefs[pos] = v * v;
    }
}

// ---------------- W transpose to bf16: Wt[l][n][k] = bf16(W[l][k][n]) ----------------

__global__ void wtrans_kernel(const float* __restrict__ W, ushort_t* __restrict__ Wt) {
    int id = blockIdx.x * 256 + threadIdx.x;  // over 6*16384
    int l = id >> 14, rem = id & 16383;
    int k = rem >> 7, n = rem & 127;
    Wt[(l << 14) + (n << 7) + k] = f2bf(W[id]);
}

// ---------------- encoder: h0 = relu(x @ Wenc + benc) + atomic BN stats ----------------

__global__ __launch_bounds__(256) void encoder_kernel(const float* __restrict__ x,
                                                      const float* __restrict__ W,
                                                      const float* __restrict__ b,
                                                      float* __restrict__ h0,
                                                      float* __restrict__ stats, int N) {
    int tid = threadIdx.x;
    int g = blockIdx.x * 256 + tid;
    int total = gridDim.x * 256;
    int c = tid & 127;
    float w0 = W[c], w1 = W[128 + c], w2 = W[256 + c], w3 = W[384 + c], bb = b[c];
    float s = 0.f, q = 0.f;
    int tot = N * 128;
    for (int i = g; i < tot; i += total) {
        int n = i >> 7;
        float4 xv = ((const float4*)x)[n];
        float v = fmaf(xv.x, w0, fmaf(xv.y, w1, fmaf(xv.z, w2, fmaf(xv.w, w3, bb))));
        v = fmaxf(v, 0.f);
        h0[i] = v;
        s += v;
        q += v * v;
    }
    __shared__ float ls[256];
    ls[tid] = s;
    __syncthreads();
    if (tid < 128) atomicAdd(&stats[tid], ls[tid] + ls[tid + 128]);
    __syncthreads();
    ls[tid] = q;
    __syncthreads();
    if (tid < 128) atomicAdd(&stats[128 + tid], ls[tid] + ls[tid + 128]);
}

// ---------------- BN stats finalize (self-zeroing for graph replay) ----------------

__global__ void finalize_stats(float* __restrict__ stats, const float* __restrict__ g,
                               const float* __restrict__ beta, float* __restrict__ ss,
                               float invN) {
    int tid = threadIdx.x;  // 128 threads
    float S = stats[tid], Q = stats[tid + 128];
    float mu = S * invN;
    float var = Q * invN - mu * mu;
    float rs = rsqrtf(var + BN_EPS);
    float scale = g[tid] * rs;
    ss[tid] = scale;
    ss[128 + tid] = beta[tid] - mu * scale;
    stats[tid] = 0.f;
    stats[tid + 128] = 0.f;
}

// ---------------- MFMA bf16 GEMM for conv layers ----------------
// MODE 0: A = h*scale + shift (encoder BN apply);  MODE 1: A = h + relu(agg*scale + shift)
// Writes updated h (f32) and hwb = bf16(A @ W)  [Wt is W^T bf16, [n][k] row-major]

#define SWZ(byte, row) ((byte) ^ (((row) & 7) << 4))

template <int MODE>
__global__ __launch_bounds__(256) void mfma_gemm(const float* __restrict__ h,
                                                 const float* __restrict__ agg,
                                                 const float* __restrict__ ss,
                                                 const ushort_t* __restrict__ Wt,
                                                 float* __restrict__ hout,
                                                 ushort_t* __restrict__ hwb, int N) {
    __shared__ ushort_t As[64 * 128];  // bf16 A-tile, XOR-swizzled rows
    const int tid = threadIdx.x;
    const int row0 = blockIdx.x * 64;

    // prologue: fused BN(/ReLU/residual) in f32, write h back, stage bf16 tile
#pragma unroll
    for (int j = 0; j < 8; j++) {
        int idx = (j * 256 + tid) * 4;
        int r = idx >> 7, c = idx & 127;
        int grow = row0 + r;
        float4 a = make_float4(0.f, 0.f, 0.f, 0.f);
        if (grow < N) {
            float4 sc = *(const float4*)&ss[c];
            float4 sh = *(const float4*)&ss[128 + c];
            float4 hv = *(const float4*)&h[(size_t)grow * 128 + c];
            if (MODE == 0) {
                a.x = fmaf(hv.x, sc.x, sh.x);
                a.y = fmaf(hv.y, sc.y, sh.y);
                a.z = fmaf(hv.z, sc.z, sh.z);
                a.w = fmaf(hv.w, sc.w, sh.w);
            } else {
                float4 av = *(const float4*)&agg[(size_t)grow * 128 + c];
                a.x = hv.x + fmaxf(fmaf(av.x, sc.x, sh.x), 0.f);
                a.y = hv.y + fmaxf(fmaf(av.y, sc.y, sh.y), 0.f);
                a.z = hv.z + fmaxf(fmaf(av.z, sc.z, sh.z), 0.f);
                a.w = hv.w + fmaxf(fmaf(av.w, sc.w, sh.w), 0.f);
            }
            *(float4*)&hout[(size_t)grow * 128 + c] = a;
        }
        uint_t p0 = f2bf(a.x) | (f2bf(a.y) << 16);
        uint_t p1 = f2bf(a.z) | (f2bf(a.w) << 16);
        *(uint2*)((char*)As + SWZ(r * 256 + c * 2, r)) = make_uint2(p0, p1);
    }
    __syncthreads();

    const int w = tid >> 6, l = tid & 63;
    const int mrow = l & 15, kg = l >> 4;
    const int arow = w * 16 + mrow;
    bf16x8 afr[4];
#pragma unroll
    for (int ks = 0; ks < 4; ks++)
        afr[ks] = *(const bf16x8*)((const char*)As + SWZ(arow * 256 + ks * 64 + kg * 16, arow));

    f32x4 acc[8];
#pragma unroll
    for (int nt = 0; nt < 8; nt++) acc[nt] = (f32x4){0.f, 0.f, 0.f, 0.f};

#pragma unroll
    for (int nt = 0; nt < 8; nt++) {
        const ushort_t* wp = &Wt[(size_t)(nt * 16 + mrow) * 128 + kg * 8];
#pragma unroll
        for (int ks = 0; ks < 4; ks++) {
            bf16x8 bfr = *(const bf16x8*)&wp[ks * 32];
            acc[nt] = __builtin_amdgcn_mfma_f32_16x16x32_bf16(afr[ks], bfr, acc[nt], 0, 0, 0);
        }
    }

    // epilogue: C[row=(l>>4)*4+r][col=l&15] per m89-verified layout
#pragma unroll
    for (int nt = 0; nt < 8; nt++) {
#pragma unroll
        for (int r = 0; r < 4; r++) {
            int grow = row0 + w * 16 + kg * 4 + r;
            if (grow < N) hwb[(size_t)grow * 128 + nt * 16 + mrow] = f2bf(acc[nt][r]);
        }
    }
}

// ---------------- f32 fused GEMM (decoder) ----------------
// MODE 1: A = h + relu(agg*scale + shift); MODE 2: A = A0 plain

template <int K, int NOUT, int MODE, bool RELU>
__global__ __launch_bounds__(256) void fused_gemm(const float* A0, const float* __restrict__ agg,
                                                  const float* __restrict__ ss,
                                                  const float* __restrict__ B,
                                                  const float* __restrict__ bias,
                                                  float* __restrict__ Cf, int N) {
    constexpr int TN = NOUT / 16;
    constexpr int LDA = K + 1;
    __shared__ float As[64 * LDA];
    __shared__ float Bs[16 * NOUT];
    const int tid = threadIdx.x;
    const int row0 = blockIdx.x * 64;

    constexpr int NF4 = 64 * K / 4 / 256;
#pragma unroll
    for (int j = 0; j < NF4; j++) {
        int idx = (j * 256 + tid) * 4;
        int r = idx / K;
        int c = idx % K;
        int grow = row0 + r;
        float4 a = make_float4(0.f, 0.f, 0.f, 0.f);
        if (grow < N) {
            if (MODE == 2) {
                a = *(const float4*)&A0[(size_t)grow * K + c];
            } else {
                float4 sc = *(const float4*)&ss[c];
                float4 sh = *(const float4*)&ss[128 + c];
                float4 hv = *(const float4*)&A0[(size_t)grow * K + c];
                float4 av = *(const float4*)&agg[(size_t)grow * K + c];
                a.x = hv.x + fmaxf(fmaf(av.x, sc.x, sh.x), 0.f);
                a.y = hv.y + fmaxf(fmaf(av.y, sc.y, sh.y), 0.f);
                a.z = hv.z + fmaxf(fmaf(av.z, sc.z, sh.z), 0.f);
                a.w = hv.w + fmaxf(fmaf(av.w, sc.w, sh.w), 0.f);
            }
        }
        As[r * LDA + c + 0] = a.x;
        As[r * LDA + c + 1] = a.y;
        As[r * LDA + c + 2] = a.z;
        As[r * LDA + c + 3] = a.w;
    }
    __syncthreads();

    float acc[4][TN];
#pragma unroll
    for (int i = 0; i < 4; i++)
#pragma unroll
        for (int j = 0; j < TN; j++) acc[i][j] = 0.f;

    const int tx = tid & 15, ty = tid >> 4;
    for (int k0 = 0; k0 < K; k0 += 16) {
        for (int f = tid; f < 16 * NOUT / 4; f += 256) {
            int r = f / (NOUT / 4), c4 = (f % (NOUT / 4)) * 4;
            *(float4*)&Bs[r * NOUT + c4] = *(const float4*)&B[(size_t)(k0 + r) * NOUT + c4];
        }
        __syncthreads();
#pragma unroll
        for (int kk = 0; kk < 16; ++kk) {
            float a[4], bf[TN];
#pragma unroll
            for (int i = 0; i < 4; i++) a[i] = As[(ty * 4 + i) * LDA + k0 + kk];
#pragma unroll
            for (int j = 0; j < TN; j++) bf[j] = Bs[kk * NOUT + tx * TN + j];
#pragma unroll
            for (int i = 0; i < 4; i++)
#pragma unroll
                for (int j = 0; j < TN; j++) acc[i][j] = fmaf(a[i], bf[j], acc[i][j]);
        }
        __syncthreads();
    }

#pragma unroll
    for (int i = 0; i < 4; i++) {
        int grow = row0 + ty * 4 + i;
        if (grow >= N) continue;
#pragma unroll
        for (int j = 0; j < TN; j++) {
            int c = tx * TN + j;
            float v = acc[i][j];
            if (bias) v += bias[c];
            if (RELU) v = fmaxf(v, 0.f);
            Cf[(size_t)grow * NOUT + c] = v;
        }
    }
}

// ---------------- aggregation: 16-lane group per node, edge loop unrolled x4 ----------------

__global__ __launch_bounds__(256) void agg_kernel(const ushort_t* __restrict__ hwb,
                                                  const int* __restrict__ rowptr,
                                                  const int* __restrict__ srcs,
                                                  const float* __restrict__ coefs,
                                                  float* __restrict__ agg,
                                                  float* __restrict__ stats, int N) {
    const int tid = threadIdx.x;
    const int wave = tid >> 6, lane = tid & 63;
    const int cbase = (lane & 15) * 8;  // 8 bf16 channels per lane
    const int grp = blockIdx.x * 16 + (tid >> 4);
    const int ngrp = gridDim.x * 16;
    float s[8], q[8];
#pragma unroll
    for (int j = 0; j < 8; j++) {
        s[j] = 0.f;
        q[j] = 0.f;
    }

    for (int n = grp; n < N; n += ngrp) {
        const int e0 = rowptr[n], e1 = rowptr[n + 1];
        float a[8];
#pragma unroll
        for (int j = 0; j < 8; j++) a[j] = 0.f;
        for (int e = e0; e < e1; e += 4) {
            int4 sv = *(const int4*)&srcs[e];       // broadcast within group
            float4 wv = *(const float4*)&coefs[e];  // broadcast within group
            uint4 g0 = *(const uint4*)&hwb[(size_t)sv.x * 128 + cbase];
            uint4 g1 = *(const uint4*)&hwb[(size_t)sv.y * 128 + cbase];
            uint4 g2 = *(const uint4*)&hwb[(size_t)sv.z * 128 + cbase];
            uint4 g3 = *(const uint4*)&hwb[(size_t)sv.w * 128 + cbase];
            acc8(a, g0, wv.x);
            acc8(a, g1, wv.y);
            acc8(a, g2, wv.z);
            acc8(a, g3, wv.w);
        }
        *(float4*)&agg[(size_t)n * 128 + cbase] = make_float4(a[0], a[1], a[2], a[3]);
        *(float4*)&agg[(size_t)n * 128 + cbase + 4] = make_float4(a[4], a[5], a[6], a[7]);
#pragma unroll
        for (int j = 0; j < 8; j++) {
            s[j] += a[j];
            q[j] += a[j] * a[j];
        }
    }

    // fold the 4 groups of each wave, then block-reduce + atomic
#pragma unroll
    for (int j = 0; j < 8; j++) {
        s[j] += __shfl_xor(s[j], 16, 64);
        s[j] += __shfl_xor(s[j], 32, 64);
        q[j] += __shfl_xor(q[j], 16, 64);
        q[j] += __shfl_xor(q[j], 32, 64);
    }
    __shared__ float ls[4][128];
    if (lane < 16) {
#pragma unroll
        for (int j = 0; j < 8; j++) ls[wave][cbase + j] = s[j];
    }
    __syncthreads();
    if (tid < 128) atomicAdd(&stats[tid], ls[0][tid] + ls[1][tid] + ls[2][tid] + ls[3][tid]);
    __syncthreads();
    if (lane < 16) {
#pragma unroll
        for (int j = 0; j < 8; j++) ls[wave][cbase + j] = q[j];
    }
    __syncthreads();
    if (tid < 128) atomicAdd(&stats[128 + tid], ls[0][tid] + ls[1][tid] + ls[2][tid] + ls[3][tid]);
}

// ---------------- decoder final: out = d2 @ W3 + b3 ----------------

__global__ void dec3_kernel(const float* __restrict__ d2, const float* __restrict__ W3,
                            const float* __restrict__ b3, float* __restrict__ out, int N) {
    __shared__ float tile[64 * 33];
    __shared__ float w3s[32];
    int base = blockIdx.x * 64;
    int tid = threadIdx.x;
    if (tid < 32) w3s[tid] = W3[tid];
    for (int f = tid; f < 2048; f += 256) {
        int r = f >> 5, c = f & 31;
        int n = base + r;
        tile[r * 33 + c] = (n < N) ? d2[(size_t)n * 32 + c] : 0.f;
    }
    __syncthreads();
    if (tid < 64) {
        int n = base + tid;
        if (n < N) {
            float s = b3[0];
#pragma unroll
            for (int k = 0; k < 32; k++) s = fmaf(tile[tid * 33 + k], w3s[k], s);
            out[n] = s;
        }
    }
}

// ---------------- host ----------------

extern "C" void kernel_launch(void* const* d_in, const int* in_sizes, int n_in, void* d_out,
                              int out_size, void* d_ws, size_t ws_size, hipStream_t stream) {
    const float* x = (const float*)d_in[0];
    const int* ei = (const int*)d_in[1];
    const float* enc_w = (const float*)d_in[2];
    const float* enc_b = (const float*)d_in[3];
    const float* enc_bn_g = (const float*)d_in[4];
    const float* enc_bn_b = (const float*)d_in[5];
    const float* conv_w = (const float*)d_in[6];
    // d_in[7] = conv_b: cancels in BatchNorm, unused
    const float* bn_g = (const float*)d_in[8];
    const float* bn_b = (const float*)d_in[9];
    const float* dw1 = (const float*)d_in[10];
    const float* db1 = (const float*)d_in[11];
    const float* dw2 = (const float*)d_in[12];
    const float* db2 = (const float*)d_in[13];
    const float* dw3 = (const float*)d_in[14];
    const float* db3 = (const float*)d_in[15];
    float* out = (float*)d_out;

    const int N = in_sizes[0] / 4;  // 50000
    const int E = in_sizes[1] / 2;  // 600000
    const size_t N128 = (size_t)N * 128;
    const int EPMAX = E + 4 * N;  // padded-CSR upper bound

    // workspace layout (~72 MB)
    float* h = (float*)d_ws;                  // N x 128 f32
    float* agg = h + N128;                    // N x 128 f32
    ushort_t* hwb = (ushort_t*)(agg + N128);  // N x 128 bf16
    ushort_t* wt = hwb + N128;                // 6 x 128 x 128 bf16 (W^T)
    float* stats = (float*)(wt + 6 * 16384);  // 256
    float* ss = stats + 256;                  // 256: scale[128], shift[128]
    float* isd = ss + 256;                    // N
    int* counts = (int*)(isd + N);            // N
    int* rowptr = counts + N;                 // N+1
    int* cursor = rowptr + N + 1;             // N
    int* srcs = cursor + N;                   // EPMAX
    float* coefs = (float*)(srcs + EPMAX);    // EPMAX
    float* d1 = (float*)hwb;                  // reuse: N x 64 f32
    float* d2 = agg;                          // reuse: N x 32 f32

    (void)hipMemsetAsync(stats, 0, 256 * sizeof(float), stream);
    (void)hipMemsetAsync(counts, 0, (size_t)N * sizeof(int), stream);
    (void)hipMemsetAsync(cursor, 0, (size_t)N * sizeof(int), stream);
    (void)hipMemsetAsync(srcs, 0, (size_t)EPMAX * sizeof(int), stream);
    (void)hipMemsetAsync(coefs, 0, (size_t)EPMAX * sizeof(float), stream);

    const int eb = (E + 255) / 256;
    const int nb = (N + 255) / 256;
    count_kernel<<<eb, 256, 0, stream>>>(ei, counts, E);
    isd_kernel<<<nb, 256, 0, stream>>>(counts, isd, N);
    scan_kernel<<<1, 256, 0, stream>>>(counts, rowptr, N);
    scatter_kernel<<<eb, 256, 0, stream>>>(ei, rowptr, cursor, isd, srcs, coefs, E);
    selfedge_kernel<<<nb, 256, 0, stream>>>(counts, rowptr, isd, srcs, coefs, N);
    wtrans_kernel<<<384, 256, 0, stream>>>(conv_w, wt);

    encoder_kernel<<<1024, 256, 0, stream>>>(x, enc_w, enc_b, h, stats, N);
    finalize_stats<<<1, 128, 0, stream>>>(stats, enc_bn_g, enc_bn_b, ss, 1.0f / N);

    const int gblocks = (N + 63) / 64;
    const float invN = 1.0f / N;

    // layer 0: A = BN(h0) (write back), hwb = A @ W0
    mfma_gemm<0><<<gblocks, 256, 0, stream>>>(h, nullptr, ss, wt, h, hwb, N);
    agg_kernel<<<1024, 256, 0, stream>>>(hwb, rowptr, srcs, coefs, agg, stats, N);
    finalize_stats<<<1, 128, 0, stream>>>(stats, bn_g, bn_b, ss, invN);

    for (int l = 1; l < 6; l++) {
        mfma_gemm<1><<<gblocks, 256, 0, stream>>>(h, agg, ss, wt + (size_t)l * 16384, h, hwb, N);
        agg_kernel<<<1024, 256, 0, stream>>>(hwb, rowptr, srcs, coefs, agg, stats, N);
        finalize_stats<<<1, 128, 0, stream>>>(stats, bn_g + l * 128, bn_b + l * 128, ss, invN);
    }

    // decoder: layer-5 update fused into dec1's prologue (h not written back)
    fused_gemm<128, 64, 1, true><<<gblocks, 256, 0, stream>>>(h, agg, ss, dw1, db1, d1, N);
    fused_gemm<64, 32, 2, true><<<gblocks, 256, 0, stream>>>(d1, nullptr, nullptr, dw2, db2, d2, N);
    dec3_kernel<<<gblocks, 256, 0, stream>>>(d2, dw3, db3, out, N);
}

// Round 6
// 657.513 us; speedup vs baseline: 1.6510x; 1.0808x over previous
//
#include <hip/hip_runtime.h>

#define BN_EPS 1e-5f

typedef unsigned int uint_t;
typedef unsigned short ushort_t;
typedef short bf16x8 __attribute__((ext_vector_type(8)));
typedef float f32x4 __attribute__((ext_vector_type(4)));

__device__ __forceinline__ float bflo(uint_t v) { return __uint_as_float(v << 16); }
__device__ __forceinline__ float bfhi(uint_t v) { return __uint_as_float(v & 0xffff0000u); }
__device__ __forceinline__ uint_t f2bf(float f) {
    uint_t u = __float_as_uint(f);
    u += 0x7fffu + ((u >> 16) & 1u);
    return u >> 16;
}

__device__ __forceinline__ void acc8(float* a, uint4 g, float w) {
    a[0] = fmaf(bflo(g.x), w, a[0]);
    a[1] = fmaf(bfhi(g.x), w, a[1]);
    a[2] = fmaf(bflo(g.y), w, a[2]);
    a[3] = fmaf(bfhi(g.y), w, a[3]);
    a[4] = fmaf(bflo(g.z), w, a[4]);
    a[5] = fmaf(bfhi(g.z), w, a[5]);
    a[6] = fmaf(bflo(g.w), w, a[6]);
    a[7] = fmaf(bfhi(g.w), w, a[7]);
}

// ---------------- CSR build (self-loop as explicit edge, rows padded to %4) ----------------

__global__ void count_kernel(const int* __restrict__ ei, int* __restrict__ counts, int E) {
    int e = blockIdx.x * blockDim.x + threadIdx.x;
    if (e < E) atomicAdd(&counts[ei[E + e]], 1);
}

// phase 1: per-block (2048 elems) local exclusive scan of padded counts; also isd
__global__ __launch_bounds__(256) void scan_part(const int* __restrict__ counts,
                                                 int* __restrict__ rowptr, int* __restrict__ bsum,
                                                 float* __restrict__ isd, int n) {
    const int tid = threadIdx.x;
    const int lane = tid & 63, wave = tid >> 6;
    __shared__ int wsum[4];
    int idx0 = blockIdx.x * 2048 + tid * 8;
    int v[8];
    int tsum = 0;
#pragma unroll
    for (int j = 0; j < 8; j++) {
        int i = idx0 + j;
        int c = (i < n) ? counts[i] : 0;
        if (i < n) isd[i] = rsqrtf((float)c + 1.0f);
        v[j] = (i < n) ? (((c + 4) >> 2) << 2) : 0;
        tsum += v[j];
    }
    int incl = tsum;
#pragma unroll
    for (int off = 1; off < 64; off <<= 1) {
        int t = __shfl_up(incl, off, 64);
        if (lane >= off) incl += t;
    }
    if (lane == 63) wsum[wave] = incl;
    __syncthreads();
    int wexcl = 0;
    for (int w2 = 0; w2 < wave; w2++) wexcl += wsum[w2];
    int run = wexcl + (incl - tsum);
#pragma unroll
    for (int j = 0; j < 8; j++) {
        int i = idx0 + j;
        if (i < n) rowptr[i] = run;
        run += v[j];
    }
    if (tid == 255) bsum[blockIdx.x] = run;
}

// phase 2: single-wave exclusive scan of block sums (nb <= 64)
__global__ void scan_mid(int* __restrict__ bsum, int nb) {
    int lane = threadIdx.x;
    int v = (lane < nb) ? bsum[lane] : 0;
    int incl = v;
#pragma unroll
    for (int off = 1; off < 64; off <<= 1) {
        int t = __shfl_up(incl, off, 64);
        if (lane >= off) incl += t;
    }
    if (lane < nb) bsum[lane] = incl - v;
    if (lane == 63) bsum[nb] = incl;  // grand total
}

// phase 3: add block offsets
__global__ void scan_add(int* __restrict__ rowptr, const int* __restrict__ bsum, int n, int nb) {
    int i = blockIdx.x * 256 + threadIdx.x;
    if (i < n)
        rowptr[i] += bsum[i >> 11];
    else if (i == n)
        rowptr[n] = bsum[nb];
}

__global__ void scatter_kernel(const int* __restrict__ ei, const int* __restrict__ rowptr,
                               int* __restrict__ cursor, const float* __restrict__ isd,
                               int* __restrict__ srcs, float* __restrict__ coefs, int E) {
    int e = blockIdx.x * blockDim.x + threadIdx.x;
    if (e < E) {
        int s = ei[e], d = ei[E + e];
        int p = atomicAdd(&cursor[d], 1);
        int idx = rowptr[d] + p;
        srcs[idx] = s;
        coefs[idx] = isd[s] * isd[d];
    }
}

// self edge + fill pad slots (src=n, coef=0) so no srcs/coefs memset is needed
__global__ void selfedge_kernel(const int* __restrict__ counts, const int* __restrict__ rowptr,
                                const float* __restrict__ isd, int* __restrict__ srcs,
                                float* __restrict__ coefs, int N) {
    int n = blockIdx.x * blockDim.x + threadIdx.x;
    if (n < N) {
        int pos = rowptr[n] + counts[n];
        int end = rowptr[n + 1];
        float v = isd[n];
        srcs[pos] = n;
        coefs[pos] = v * v;
        for (int p = pos + 1; p < end; p++) {
            srcs[p] = n;
            coefs[p] = 0.f;
        }
    }
}

// ---------------- W transpose to bf16: Wt[l][n][k] = bf16(W[l][k][n]) ----------------

__global__ void wtrans_kernel(const float* __restrict__ W, ushort_t* __restrict__ Wt) {
    int id = blockIdx.x * 256 + threadIdx.x;  // over 6*16384
    int l = id >> 14, rem = id & 16383;
    int k = rem >> 7, n = rem & 127;
    Wt[(l << 14) + (n << 7) + k] = f2bf(W[id]);
}

// ---------------- encoder: h0 = relu(x @ Wenc + benc) + atomic BN stats (slot 0) ----------------

__global__ __launch_bounds__(256) void encoder_kernel(const float* __restrict__ x,
                                                      const float* __restrict__ W,
                                                      const float* __restrict__ b,
                                                      float* __restrict__ h0,
                                                      float* __restrict__ stats, int N) {
    int tid = threadIdx.x;
    int g = blockIdx.x * 256 + tid;
    int total = gridDim.x * 256;
    int c = tid & 127;
    float w0 = W[c], w1 = W[128 + c], w2 = W[256 + c], w3 = W[384 + c], bb = b[c];
    float s = 0.f, q = 0.f;
    int tot = N * 128;
    for (int i = g; i < tot; i += total) {
        int n = i >> 7;
        float4 xv = ((const float4*)x)[n];
        float v = fmaf(xv.x, w0, fmaf(xv.y, w1, fmaf(xv.z, w2, fmaf(xv.w, w3, bb))));
        v = fmaxf(v, 0.f);
        h0[i] = v;
        s += v;
        q += v * v;
    }
    __shared__ float ls[256];
    ls[tid] = s;
    __syncthreads();
    if (tid < 128) atomicAdd(&stats[tid], ls[tid] + ls[tid + 128]);
    __syncthreads();
    ls[tid] = q;
    __syncthreads();
    if (tid < 128) atomicAdd(&stats[128 + tid], ls[tid] + ls[tid + 128]);
}

// ---------------- MFMA bf16 GEMM for conv layers ----------------
// Computes scale/shift from stats in-prologue (no separate finalize kernel).
// MODE 0: A = h*sc + sh;  MODE 1: A = h + relu(aggb*sc + sh)  (aggb bf16)
// Writes updated h (f32) and hwb = bf16(A @ W)  [Wt = W^T bf16, [n][k] row-major]

#define SWZ(byte, row) ((byte) ^ (((row) & 7) << 4))

template <int MODE>
__global__ __launch_bounds__(256) void mfma_gemm(const float* __restrict__ h,
                                                 const ushort_t* __restrict__ aggb,
                                                 const float* __restrict__ stats,
                                                 const float* __restrict__ g,
                                                 const float* __restrict__ beta, float invN,
                                                 const ushort_t* __restrict__ Wt,
                                                 float* __restrict__ hout,
                                                 ushort_t* __restrict__ hwb, int N) {
    __shared__ ushort_t As[64 * 128];  // bf16 A-tile, XOR-swizzled rows
    __shared__ float s_sc[128], s_sh[128];
    const int tid = threadIdx.x;
    const int row0 = blockIdx.x * 64;

    if (tid < 128) {
        float S = stats[tid], Q = stats[tid + 128];
        float mu = S * invN;
        float var = fmaxf(Q * invN - mu * mu, 0.f);
        float rs = rsqrtf(var + BN_EPS);
        float sc = g[tid] * rs;
        s_sc[tid] = sc;
        s_sh[tid] = beta[tid] - mu * sc;
    }
    __syncthreads();

    // prologue: fused BN(/ReLU/residual) in f32, write h back, stage bf16 tile
#pragma unroll
    for (int j = 0; j < 4; j++) {
        int idx = (j * 256 + tid) * 8;
        int r = idx >> 7, c = idx & 127;
        int grow = row0 + r;
        float av[8] = {0.f, 0.f, 0.f, 0.f, 0.f, 0.f, 0.f, 0.f};
        if (grow < N) {
            float4 h0 = *(const float4*)&h[(size_t)grow * 128 + c];
            float4 h1 = *(const float4*)&h[(size_t)grow * 128 + c + 4];
            float hv[8] = {h0.x, h0.y, h0.z, h0.w, h1.x, h1.y, h1.z, h1.w};
            if (MODE == 0) {
#pragma unroll
                for (int k = 0; k < 8; k++) av[k] = fmaf(hv[k], s_sc[c + k], s_sh[c + k]);
            } else {
                uint4 ag = *(const uint4*)&aggb[(size_t)grow * 128 + c];
                float ga[8] = {bflo(ag.x), bfhi(ag.x), bflo(ag.y), bfhi(ag.y),
                               bflo(ag.z), bfhi(ag.z), bflo(ag.w), bfhi(ag.w)};
#pragma unroll
                for (int k = 0; k < 8; k++)
                    av[k] = hv[k] + fmaxf(fmaf(ga[k], s_sc[c + k], s_sh[c + k]), 0.f);
            }
            *(float4*)&hout[(size_t)grow * 128 + c] = make_float4(av[0], av[1], av[2], av[3]);
            *(float4*)&hout[(size_t)grow * 128 + c + 4] = make_float4(av[4], av[5], av[6], av[7]);
        }
        uint4 p;
        p.x = f2bf(av[0]) | (f2bf(av[1]) << 16);
        p.y = f2bf(av[2]) | (f2bf(av[3]) << 16);
        p.z = f2bf(av[4]) | (f2bf(av[5]) << 16);
        p.w = f2bf(av[6]) | (f2bf(av[7]) << 16);
        *(uint4*)((char*)As + SWZ(r * 256 + c * 2, r)) = p;
    }
    __syncthreads();

    const int w = tid >> 6, l = tid & 63;
    const int mrow = l & 15, kg = l >> 4;
    const int arow = w * 16 + mrow;
    bf16x8 afr[4];
#pragma unroll
    for (int ks = 0; ks < 4; ks++)
        afr[ks] = *(const bf16x8*)((const char*)As + SWZ(arow * 256 + ks * 64 + kg * 16, arow));

    f32x4 acc[8];
#pragma unroll
    for (int nt = 0; nt < 8; nt++) acc[nt] = (f32x4){0.f, 0.f, 0.f, 0.f};

#pragma unroll
    for (int nt = 0; nt < 8; nt++) {
        const ushort_t* wp = &Wt[(size_t)(nt * 16 + mrow) * 128 + kg * 8];
#pragma unroll
        for (int ks = 0; ks < 4; ks++) {
            bf16x8 bfr = *(const bf16x8*)&wp[ks * 32];
            acc[nt] = __builtin_amdgcn_mfma_f32_16x16x32_bf16(afr[ks], bfr, acc[nt], 0, 0, 0);
        }
    }

    // epilogue: C[row=(l>>4)*4+r][col=l&15] per m89-verified layout
#pragma unroll
    for (int nt = 0; nt < 8; nt++) {
#pragma unroll
        for (int r = 0; r < 4; r++) {
            int grow = row0 + w * 16 + kg * 4 + r;
            if (grow < N) hwb[(size_t)grow * 128 + nt * 16 + mrow] = f2bf(acc[nt][r]);
        }
    }
}

// ---------------- f32 fused GEMM (decoder) ----------------
// MODE 1: A = h + relu(aggb*sc + sh)  (stats in-prologue); MODE 2: A = A0 plain

template <int K, int NOUT, int MODE, bool RELU>
__global__ __launch_bounds__(256) void fused_gemm(const float* __restrict__ A0,
                                                  const ushort_t* __restrict__ aggb,
                                                  const float* __restrict__ stats,
                                                  const float* __restrict__ g,
                                                  const float* __restrict__ beta, float invN,
                                                  const float* __restrict__ B,
                                                  const float* __restrict__ bias,
                                                  float* __restrict__ Cf, int N) {
    constexpr int TN = NOUT / 16;
    constexpr int LDA = K + 1;
    __shared__ float As[64 * LDA];
    __shared__ float Bs[16 * NOUT];
    __shared__ float s_sc[128], s_sh[128];
    const int tid = threadIdx.x;
    const int row0 = blockIdx.x * 64;

    if (MODE == 1) {
        if (tid < 128) {
            float S = stats[tid], Q = stats[tid + 128];
            float mu = S * invN;
            float var = fmaxf(Q * invN - mu * mu, 0.f);
            float rs = rsqrtf(var + BN_EPS);
            float sc = g[tid] * rs;
            s_sc[tid] = sc;
            s_sh[tid] = beta[tid] - mu * sc;
        }
        __syncthreads();
#pragma unroll
        for (int j = 0; j < 4; j++) {
            int idx = (j * 256 + tid) * 8;
            int r = idx >> 7, c = idx & 127;
            int grow = row0 + r;
            float av[8] = {0.f, 0.f, 0.f, 0.f, 0.f, 0.f, 0.f, 0.f};
            if (grow < N) {
                float4 h0 = *(const float4*)&A0[(size_t)grow * 128 + c];
                float4 h1 = *(const float4*)&A0[(size_t)grow * 128 + c + 4];
                float hv[8] = {h0.x, h0.y, h0.z, h0.w, h1.x, h1.y, h1.z, h1.w};
                uint4 ag = *(const uint4*)&aggb[(size_t)grow * 128 + c];
                float ga[8] = {bflo(ag.x), bfhi(ag.x), bflo(ag.y), bfhi(ag.y),
                               bflo(ag.z), bfhi(ag.z), bflo(ag.w), bfhi(ag.w)};
#pragma unroll
                for (int k = 0; k < 8; k++)
                    av[k] = hv[k] + fmaxf(fmaf(ga[k], s_sc[c + k], s_sh[c + k]), 0.f);
            }
#pragma unroll
            for (int k = 0; k < 8; k++) As[r * LDA + c + k] = av[k];
        }
    } else {
        constexpr int NF4 = 64 * K / 4 / 256;
#pragma unroll
        for (int j = 0; j < NF4; j++) {
            int idx = (j * 256 + tid) * 4;
            int r = idx / K;
            int c = idx % K;
            int grow = row0 + r;
            float4 a = make_float4(0.f, 0.f, 0.f, 0.f);
            if (grow < N) a = *(const float4*)&A0[(size_t)grow * K + c];
            As[r * LDA + c + 0] = a.x;
            As[r * LDA + c + 1] = a.y;
            As[r * LDA + c + 2] = a.z;
            As[r * LDA + c + 3] = a.w;
        }
    }
    __syncthreads();

    float acc[4][TN];
#pragma unroll
    for (int i = 0; i < 4; i++)
#pragma unroll
        for (int j = 0; j < TN; j++) acc[i][j] = 0.f;

    const int tx = tid & 15, ty = tid >> 4;
    for (int k0 = 0; k0 < K; k0 += 16) {
        for (int f = tid; f < 16 * NOUT / 4; f += 256) {
            int r = f / (NOUT / 4), c4 = (f % (NOUT / 4)) * 4;
            *(float4*)&Bs[r * NOUT + c4] = *(const float4*)&B[(size_t)(k0 + r) * NOUT + c4];
        }
        __syncthreads();
#pragma unroll
        for (int kk = 0; kk < 16; ++kk) {
            float a[4], bf[TN];
#pragma unroll
            for (int i = 0; i < 4; i++) a[i] = As[(ty * 4 + i) * LDA + k0 + kk];
#pragma unroll
            for (int j = 0; j < TN; j++) bf[j] = Bs[kk * NOUT + tx * TN + j];
#pragma unroll
            for (int i = 0; i < 4; i++)
#pragma unroll
                for (int j = 0; j < TN; j++) acc[i][j] = fmaf(a[i], bf[j], acc[i][j]);
        }
        __syncthreads();
    }

#pragma unroll
    for (int i = 0; i < 4; i++) {
        int grow = row0 + ty * 4 + i;
        if (grow >= N) continue;
#pragma unroll
        for (int j = 0; j < TN; j++) {
            int c = tx * TN + j;
            float v = acc[i][j];
            if (bias) v += bias[c];
            if (RELU) v = fmaxf(v, 0.f);
            Cf[(size_t)grow * NOUT + c] = v;
        }
    }
}

// ---------------- aggregation: pair of nodes per 16-lane group, branchless x8 gathers ----------------
// aggb[n] = bf16( sum_edges hwb[src]*coef ), self loop is an explicit edge; + BN stats

__global__ __launch_bounds__(256) void agg_kernel(const ushort_t* __restrict__ hwb,
                                                  const int* __restrict__ rowptr,
                                                  const int* __restrict__ srcs,
                                                  const float* __restrict__ coefs,
                                                  ushort_t* __restrict__ aggb,
                                                  float* __restrict__ stats, int N) {
    const int tid = threadIdx.x;
    const int wave = tid >> 6, lane = tid & 63;
    const int cbase = (lane & 15) * 8;  // 8 bf16 channels per lane
    const int grp = blockIdx.x * 16 + (tid >> 4);
    float s[8], q[8];
#pragma unroll
    for (int j = 0; j < 8; j++) {
        s[j] = 0.f;
        q[j] = 0.f;
    }

    const int n0 = grp * 2;
    if (n0 < N) {
        const int n1 = n0 + 1;
        const bool hasB = n1 < N;
        int ea = rowptr[n0];
        const int eaE = rowptr[n0 + 1];
        int eb = eaE;
        const int ebE = hasB ? rowptr[n1 + 1] : eaE;
        float aA[8] = {0.f, 0.f, 0.f, 0.f, 0.f, 0.f, 0.f, 0.f};
        float aB[8] = {0.f, 0.f, 0.f, 0.f, 0.f, 0.f, 0.f, 0.f};
        while (ea < eaE || eb < ebE) {
            int ca = min(ea, eaE - 4), cb = min(eb, ebE - 4);
            int4 svA = *(const int4*)&srcs[ca];
            float4 wvA = *(const float4*)&coefs[ca];
            int4 svB = *(const int4*)&srcs[cb];
            float4 wvB = *(const float4*)&coefs[cb];
            if (ea >= eaE) wvA = make_float4(0.f, 0.f, 0.f, 0.f);
            if (eb >= ebE) wvB = make_float4(0.f, 0.f, 0.f, 0.f);
            uint4 gA0 = *(const uint4*)&hwb[(size_t)svA.x * 128 + cbase];
            uint4 gA1 = *(const uint4*)&hwb[(size_t)svA.y * 128 + cbase];
            uint4 gA2 = *(const uint4*)&hwb[(size_t)svA.z * 128 + cbase];
            uint4 gA3 = *(const uint4*)&hwb[(size_t)svA.w * 128 + cbase];
            uint4 gB0 = *(const uint4*)&hwb[(size_t)svB.x * 128 + cbase];
            uint4 gB1 = *(const uint4*)&hwb[(size_t)svB.y * 128 + cbase];
            uint4 gB2 = *(const uint4*)&hwb[(size_t)svB.z * 128 + cbase];
            uint4 gB3 = *(const uint4*)&hwb[(size_t)svB.w * 128 + cbase];
            acc8(aA, gA0, wvA.x);
            acc8(aA, gA1, wvA.y);
            acc8(aA, gA2, wvA.z);
            acc8(aA, gA3, wvA.w);
            acc8(aB, gB0, wvB.x);
            acc8(aB, gB1, wvB.y);
            acc8(aB, gB2, wvB.z);
            acc8(aB, gB3, wvB.w);
            ea = min(ea + 4, eaE);
            eb = min(eb + 4, ebE);
        }
        uint4 pA;
        pA.x = f2bf(aA[0]) | (f2bf(aA[1]) << 16);
        pA.y = f2bf(aA[2]) | (f2bf(aA[3]) << 16);
        pA.z = f2bf(aA[4]) | (f2bf(aA[5]) << 16);
        pA.w = f2bf(aA[6]) | (f2bf(aA[7]) << 16);
        *(uint4*)&aggb[(size_t)n0 * 128 + cbase] = pA;
#pragma unroll
        for (int j = 0; j < 8; j++) {
            s[j] += aA[j];
            q[j] += aA[j] * aA[j];
        }
        if (hasB) {
            uint4 pB;
            pB.x = f2bf(aB[0]) | (f2bf(aB[1]) << 16);
            pB.y = f2bf(aB[2]) | (f2bf(aB[3]) << 16);
            pB.z = f2bf(aB[4]) | (f2bf(aB[5]) << 16);
            pB.w = f2bf(aB[6]) | (f2bf(aB[7]) << 16);
            *(uint4*)&aggb[(size_t)n1 * 128 + cbase] = pB;
#pragma unroll
            for (int j = 0; j < 8; j++) {
                s[j] += aB[j];
                q[j] += aB[j] * aB[j];
            }
        }
    }

    // fold 4 groups per wave, then block-reduce + atomic into this layer's stats slot
#pragma unroll
    for (int j = 0; j < 8; j++) {
        s[j] += __shfl_xor(s[j], 16, 64);
        s[j] += __shfl_xor(s[j], 32, 64);
        q[j] += __shfl_xor(q[j], 16, 64);
        q[j] += __shfl_xor(q[j], 32, 64);
    }
    __shared__ float ls[4][128];
    if (lane < 16) {
#pragma unroll
        for (int j = 0; j < 8; j++) ls[wave][cbase + j] = s[j];
    }
    __syncthreads();
    if (tid < 128) atomicAdd(&stats[tid], ls[0][tid] + ls[1][tid] + ls[2][tid] + ls[3][tid]);
    __syncthreads();
    if (lane < 16) {
#pragma unroll
        for (int j = 0; j < 8; j++) ls[wave][cbase + j] = q[j];
    }
    __syncthreads();
    if (tid < 128) atomicAdd(&stats[128 + tid], ls[0][tid] + ls[1][tid] + ls[2][tid] + ls[3][tid]);
}

// ---------------- decoder final: out = d2 @ W3 + b3 ----------------

__global__ void dec3_kernel(const float* __restrict__ d2, const float* __restrict__ W3,
                            const float* __restrict__ b3, float* __restrict__ out, int N) {
    __shared__ float tile[64 * 33];
    __shared__ float w3s[32];
    int base = blockIdx.x * 64;
    int tid = threadIdx.x;
    if (tid < 32) w3s[tid] = W3[tid];
    for (int f = tid; f < 2048; f += 256) {
        int r = f >> 5, c = f & 31;
        int n = base + r;
        tile[r * 33 + c] = (n < N) ? d2[(size_t)n * 32 + c] : 0.f;
    }
    __syncthreads();
    if (tid < 64) {
        int n = base + tid;
        if (n < N) {
            float s = b3[0];
#pragma unroll
            for (int k = 0; k < 32; k++) s = fmaf(tile[tid * 33 + k], w3s[k], s);
            out[n] = s;
        }
    }
}

// ---------------- host ----------------

extern "C" void kernel_launch(void* const* d_in, const int* in_sizes, int n_in, void* d_out,
                              int out_size, void* d_ws, size_t ws_size, hipStream_t stream) {
    const float* x = (const float*)d_in[0];
    const int* ei = (const int*)d_in[1];
    const float* enc_w = (const float*)d_in[2];
    const float* enc_b = (const float*)d_in[3];
    const float* enc_bn_g = (const float*)d_in[4];
    const float* enc_bn_b = (const float*)d_in[5];
    const float* conv_w = (const float*)d_in[6];
    // d_in[7] = conv_b: cancels in BatchNorm, unused
    const float* bn_g = (const float*)d_in[8];
    const float* bn_b = (const float*)d_in[9];
    const float* dw1 = (const float*)d_in[10];
    const float* db1 = (const float*)d_in[11];
    const float* dw2 = (const float*)d_in[12];
    const float* db2 = (const float*)d_in[13];
    const float* dw3 = (const float*)d_in[14];
    const float* db3 = (const float*)d_in[15];
    float* out = (float*)d_out;

    const int N = in_sizes[0] / 4;  // 50000
    const int E = in_sizes[1] / 2;  // 600000
    const size_t N128 = (size_t)N * 128;
    const int EPMAX = E + 4 * N;  // padded-CSR upper bound
    const float invN = 1.0f / N;

    // workspace layout (~59 MB)
    float* h = (float*)d_ws;                   // N x 128 f32
    ushort_t* aggb = (ushort_t*)(h + N128);    // N x 128 bf16
    ushort_t* hwb = aggb + N128;               // N x 128 bf16
    ushort_t* wt = hwb + N128;                 // 6 x 128 x 128 bf16 (W^T)
    float* stats = (float*)(wt + 6 * 16384);   // 7 x 256 (slot l: sum/sumsq)
    float* isd = stats + 7 * 256;              // N
    int* counts = (int*)(isd + N);             // N
    int* rowptr = counts + N;                  // N+1
    int* cursor = rowptr + N + 1;              // N
    int* bsum = cursor + N;                    // 65+1
    int* srcs = bsum + 66;                     // EPMAX
    float* coefs = (float*)(srcs + EPMAX);     // EPMAX
    float* d1 = (float*)hwb;                   // reuse: N x 64 f32
    float* d2 = (float*)aggb;                  // reuse: N x 32 f32

    (void)hipMemsetAsync(stats, 0, 7 * 256 * sizeof(float), stream);
    (void)hipMemsetAsync(counts, 0, (size_t)N * sizeof(int), stream);
    (void)hipMemsetAsync(cursor, 0, (size_t)N * sizeof(int), stream);

    const int eb = (E + 255) / 256;
    const int nb = (N + 255) / 256;
    const int snb = (N + 2047) / 2048;  // scan blocks (<=64)
    count_kernel<<<eb, 256, 0, stream>>>(ei, counts, E);
    scan_part<<<snb, 256, 0, stream>>>(counts, rowptr, bsum, isd, N);
    scan_mid<<<1, 64, 0, stream>>>(bsum, snb);
    scan_add<<<(N + 256) / 256, 256, 0, stream>>>(rowptr, bsum, N, snb);
    scatter_kernel<<<eb, 256, 0, stream>>>(ei, rowptr, cursor, isd, srcs, coefs, E);
    selfedge_kernel<<<nb, 256, 0, stream>>>(counts, rowptr, isd, srcs, coefs, N);
    wtrans_kernel<<<384, 256, 0, stream>>>(conv_w, wt);

    encoder_kernel<<<1024, 256, 0, stream>>>(x, enc_w, enc_b, h, stats, N);

    const int gblocks = (N + 63) / 64;
    const int ablocks = ((N + 1) / 2 + 15) / 16;

    // layer 0: A = BN(h0) (write back), hwb = A @ W0; stats slot0 from encoder
    mfma_gemm<0><<<gblocks, 256, 0, stream>>>(h, nullptr, stats, enc_bn_g, enc_bn_b, invN, wt, h,
                                              hwb, N);
    agg_kernel<<<ablocks, 256, 0, stream>>>(hwb, rowptr, srcs, coefs, aggb, stats + 256, N);

    for (int l = 1; l < 6; l++) {
        mfma_gemm<1><<<gblocks, 256, 0, stream>>>(h, aggb, stats + l * 256, bn_g + (l - 1) * 128,
                                                  bn_b + (l - 1) * 128, invN,
                                                  wt + (size_t)l * 16384, h, hwb, N);
        agg_kernel<<<ablocks, 256, 0, stream>>>(hwb, rowptr, srcs, coefs, aggb,
                                                stats + (l + 1) * 256, N);
    }

    // decoder: layer-5 update fused into dec1's prologue (h not written back)
    fused_gemm<128, 64, 1, true><<<gblocks, 256, 0, stream>>>(
        h, aggb, stats + 6 * 256, bn_g + 5 * 128, bn_b + 5 * 128, invN, dw1, db1, d1, N);
    fused_gemm<64, 32, 2, true><<<gblocks, 256, 0, stream>>>(d1, nullptr, nullptr, nullptr,
                                                             nullptr, 0.f, dw2, db2, d2, N);
    dec3_kernel<<<gblocks, 256, 0, stream>>>(d2, dw3, db3, out, N);
}